// Round 2
// baseline (247.307 us; speedup 1.0000x reference)
//
#include <hip/hip_runtime.h>

// FWHT along axis 1 of (64, 1024, 512) fp32, unnormalized (a+b, a-b), h=1..512.
// One HBM pass: H_1024 = (H_64 (x) I_16) o (I_64 (x) H_16); stages commute.
// Round 4: pin the cross-tile prefetch with inline-asm global_load_dwordx4.
// Evidence: VGPR_Count=128 < the >=140 an honest double buffer needs, so the
// compiler was sinking the prefetch loads to their use -> demand loads ->
// iteration time ~2x the overlapped-memory model (21.6 vs ~10.4 us/tile).
// Changes vs round 3:
//  - no vn[]/rotate: prefetch overwrites v[] right after Phase C's barrier
//    (lgkmcnt(0) there has drained the ds_writes that source v -> WAR safe).
//  - loads are asm volatile (un-sinkable), 32-bit voffset + SGPR base.
//  - manual counted waits: t=0 vmcnt(0); t>=1 vmcnt(16) = "16 stores from
//    phase F may stay in flight, all 16 prefetch loads retired" (vmcnt
//    retires in order; loads are older than the stores by program order,
//    both pinned by the volatile barriers).
//  - sched_barrier(0) after each manual wait (guide rule #18: hipcc hoists
//    register-only VALU past inline-asm waitcnt despite "memory" clobber).
// Layout (unchanged from round 3): DC=32 -> full 128 B L2 lines per row,
// LDS 128 KB row-major [1024][32], D/E 2 lanes/bank (free), C/F at the
// 8-cycle wave floor. Raw s_barrier (no vmcnt drain) throughout.

constexpr int NB = 64;    // batch
constexpr int NR = 1024;  // transform length (axis 1)
constexpr int ND = 512;   // inner dim
constexpr int DC = 32;    // columns per tile -> 128 B per row per block
constexpr int TPB = 512;
constexpr int GRID = 256;                     // 1 block/CU, all resident
constexpr int TPT = (NB * (ND / DC)) / GRID;  // 4 tiles per block

// Workgroup barrier WITHOUT the compiler's vmcnt(0) drain: LDS ops must be
// complete (lgkmcnt 0) but global loads/stores may remain in flight.
#define BAR() asm volatile("s_waitcnt lgkmcnt(0)\n\ts_barrier" ::: "memory")

// Pinned 16 B load: dst <- x[byte_off], SGPR base + 32-bit voffset.
#define GLOAD(dst, off) \
    asm volatile("global_load_dwordx4 %0, %1, %2" \
                 : "=v"(dst) : "v"(off), "s"(x) : "memory")

__global__ __launch_bounds__(TPB, 2)
void fwht_kernel(const float* __restrict__ x, float* __restrict__ y) {
    __shared__ float lds[NR * DC];  // 131072 B

    const int tid = threadIdx.x;
    const int pid = blockIdx.x;     // 0..255
    const int b   = pid & 63;       // batch (invariant across tiles)
    const int dg0 = pid >> 6;       // 0..3; tile t uses dg = dg0 + 4t

    const int g  = tid >> 3;  // phase A/C/F row-group [0,64)
    const int w  = tid & 7;   // phase A/C/F col-quad  [0,8)  (w*4 in [0,32))
    const int j2 = tid >> 5;  // phase D/E row-in-group [0,16)
    const int c  = tid & 31;  // phase D/E column       [0,32)

    // element offset of (row 16g, col quad w) in batch b; fits 32-bit bytes
    const size_t rowA   = ((size_t)b * NR + (size_t)g * 16) * ND + (size_t)(w * 4);
    const uint32_t baseB = (uint32_t)(rowA * sizeof(float));  // byte offset

    float4 v[16];

    // ---- preload tile 0 (pinned) ----
    {
        const uint32_t o0 = baseB + (uint32_t)(dg0 * DC) * 4u;
#pragma unroll
        for (int j = 0; j < 16; ++j) {
            const uint32_t off = o0 + (uint32_t)(j * ND) * 4u;
            GLOAD(v[j], off);
        }
    }

#pragma unroll
    for (int t = 0; t < TPT; ++t) {
        const int dbase = (dg0 + 4 * t) * DC;

        // ---- wait for this tile's loads; stores may stay in flight ----
        if (t == 0) {
            asm volatile("s_waitcnt vmcnt(0)" ::: "memory");
        } else {
            // outstanding (oldest..newest): 16 loads (iter t-1), 16 stores
            // (phase F, iter t-1). In-order retirement => vmcnt(16) == all
            // loads landed.
            asm volatile("s_waitcnt vmcnt(16)" ::: "memory");
        }
        __builtin_amdgcn_sched_barrier(0);  // rule #18: don't hoist VALU above

        // ---- Pass 1: H_16 across j (stages h=1,2,4,8) ----
#pragma unroll
        for (int hb = 1; hb < 16; hb <<= 1) {
#pragma unroll
            for (int j = 0; j < 16; ++j) {
                if ((j & hb) == 0) {
                    const int k = j | hb;
                    float4 a = v[j], bb = v[k];
                    v[j] = make_float4(a.x + bb.x, a.y + bb.y, a.z + bb.z, a.w + bb.w);
                    v[k] = make_float4(a.x - bb.x, a.y - bb.y, a.z - bb.z, a.w - bb.w);
                }
            }
        }

        // ---- Phase C: regs -> LDS, row-major [1024][32], float4 writes ----
        {
            float4* lp = reinterpret_cast<float4*>(lds) + (size_t)g * 128 + w;
#pragma unroll
            for (int j = 0; j < 16; ++j)
                lp[j * 8] = v[j];
        }
        BAR();  // lgkmcnt(0): phase-C ds_writes (sourcing v) fully complete

        // ---- prefetch tile t+1 into v (pinned; in flight across D..F) ----
        if (t < TPT - 1) {
            const uint32_t on = baseB + (uint32_t)(dbase + 4 * DC) * 4u;
#pragma unroll
            for (int j = 0; j < 16; ++j) {
                const uint32_t off = on + (uint32_t)(j * ND) * 4u;
                GLOAD(v[j], off);
            }
        }

        // ---- Phase D: LDS -> regs, one column per thread ----
        // word = i*512 + j2*32 + c -> bank = c; 2 lanes/bank (j2 pair) = free.
        float u[64];
#pragma unroll
        for (int i = 0; i < 64; ++i)
            u[i] = lds[i * 512 + j2 * 32 + c];

        // ---- Pass 2: H_64 across i (stages h=16..512) ----
#pragma unroll
        for (int hb = 1; hb < 64; hb <<= 1) {
#pragma unroll
            for (int i = 0; i < 64; ++i) {
                if ((i & hb) == 0) {
                    const int k = i | hb;
                    float a = u[i], bb = u[k];
                    u[i] = a + bb;
                    u[k] = a - bb;
                }
            }
        }
        BAR();  // all phase-D reads done before phase E overwrites

        // ---- Phase E: u -> LDS, same row-major layout (free, 2 lanes/bank) ----
#pragma unroll
        for (int i = 0; i < 64; ++i)
            lds[i * 512 + j2 * 32 + c] = u[i];
        BAR();

        // ---- Phase F: LDS -> float4 regs -> 16x global_store_dwordx4 ----
        // 8 w-lanes/row x 16 B = 128 B contiguous per row: full lines, no RMW.
        {
            float* dst = y + rowA + dbase;
            const float4* lp = reinterpret_cast<const float4*>(lds) + (size_t)g * 128 + w;
#pragma unroll
            for (int j = 0; j < 16; ++j)
                *reinterpret_cast<float4*>(dst + (size_t)j * ND) = lp[j * 8];
        }
        BAR();  // all phase-F reads done before next iter's phase-C writes
    }
}

extern "C" void kernel_launch(void* const* d_in, const int* in_sizes, int n_in,
                              void* d_out, int out_size, void* d_ws, size_t ws_size,
                              hipStream_t stream) {
    const float* x = (const float*)d_in[0];
    float* y = (float*)d_out;
    fwht_kernel<<<dim3(GRID), dim3(TPB), 0, stream>>>(x, y);
}

// Round 3
// 246.596 us; speedup vs baseline: 1.0029x; 1.0029x over previous
//
#include <hip/hip_runtime.h>

// FWHT along axis 1 of (64, 1024, 512) fp32, unnormalized (a+b, a-b), h=1..512.
// One HBM pass: H_1024 = (H_64 (x) I_16) o (I_64 (x) H_16); stages commute.
// Round 5: kill the serial chain, not the bandwidth. Evidence from R3/R4:
// nothing is saturated (HBM 35%, VALU 7%, LDS pipe ~19%) yet iter time ~22.5us
// == sum of the serialized phases across 4 barriers in ONE lockstep block/CU.
// Changes vs round 4:
//  - Phases E and F DELETED. After Pass 2, u[i] is output element
//    (row 16i+j2, col c); a wave (2 j2-rows x 32 c) covers two full 128 B
//    lines per store instruction -> direct global_store_dword from registers
//    is fully coalesced and full-line. Saves ~4500 LDS cycles/iter/CU (half
//    of all LDS traffic) and 2 of 4 barriers.
//  - Steady-state wait is vmcnt(63): outstanding at the wait are 16 loads
//    (older) + 64 stores (newer); in-order retirement means <=63 outstanding
//    implies all 16 loads landed. (vmcnt field caps at 63; costs 1 store.)
//  - Loads AND stores are pinned asm volatile with SGPR base + 32-bit
//    voffset, so the compiler can neither sink the prefetch nor insert a
//    vmcnt(0) drain anywhere in the loop.
// Kept from round 3/4: DC=32 full-line I/O, LDS 128 KB row-major [1024][32]
// (C at the b128 wave floor, D 2 lanes/bank = free), raw s_barrier (lgkmcnt
// only), sched_barrier(0) after manual waits (guide rule #18).

constexpr int NB = 64;    // batch
constexpr int NR = 1024;  // transform length (axis 1)
constexpr int ND = 512;   // inner dim
constexpr int DC = 32;    // columns per tile -> 128 B per row per block
constexpr int TPB = 512;
constexpr int GRID = 256;                     // 1 block/CU, all resident
constexpr int TPT = (NB * (ND / DC)) / GRID;  // 4 tiles per block

// Workgroup barrier WITHOUT the compiler's vmcnt(0) drain: LDS ops must be
// complete (lgkmcnt 0) but global loads/stores may remain in flight.
#define BAR() asm volatile("s_waitcnt lgkmcnt(0)\n\ts_barrier" ::: "memory")

// Pinned 16 B load: dst <- x[byte_off], SGPR base + 32-bit voffset.
#define GLOAD(dst, off) \
    asm volatile("global_load_dwordx4 %0, %1, %2" \
                 : "=v"(dst) : "v"(off), "s"(x) : "memory")

// Pinned 4 B store: y[byte_off] <- val.
#define GSTORE(off, val) \
    asm volatile("global_store_dword %0, %1, %2" \
                 :: "v"(off), "v"(val), "s"(y) : "memory")

__global__ __launch_bounds__(TPB, 2)
void fwht_kernel(const float* __restrict__ x, float* __restrict__ y) {
    __shared__ float lds[NR * DC];  // 131072 B

    const int tid = threadIdx.x;
    const int pid = blockIdx.x;     // 0..255
    const int b   = pid & 63;       // batch (invariant across tiles)
    const int dg0 = pid >> 6;       // 0..3; tile t uses dg = dg0 + 4t

    const int g  = tid >> 3;  // phase A/C row-group [0,64)
    const int w  = tid & 7;   // phase A/C col-quad  [0,8)  (w*4 in [0,32))
    const int j2 = tid >> 5;  // phase D/store row-in-group [0,16)
    const int c  = tid & 31;  // phase D/store column       [0,32)

    // load-side base: (row 16g, col quad w) in batch b, bytes (fits 32-bit)
    const size_t rowA    = ((size_t)b * NR + (size_t)g * 16) * ND + (size_t)(w * 4);
    const uint32_t baseB = (uint32_t)(rowA * sizeof(float));
    // store-side base: (row j2, col c) in batch b, bytes; row step for u[i]
    // is 16 rows = 16*ND*4 = 32768 B
    const uint32_t baseS = (uint32_t)((((size_t)b * NR + (size_t)j2) * ND + (size_t)c) * sizeof(float));

    float4 v[16];

    // ---- preload tile 0 (pinned) ----
    {
        const uint32_t o0 = baseB + (uint32_t)(dg0 * DC) * 4u;
#pragma unroll
        for (int j = 0; j < 16; ++j)
            GLOAD(v[j], o0 + (uint32_t)(j * ND) * 4u);
    }

#pragma unroll
    for (int t = 0; t < TPT; ++t) {
        const int dbase = (dg0 + 4 * t) * DC;

        // ---- wait for this tile's loads; stores may stay in flight ----
        if (t == 0) {
            asm volatile("s_waitcnt vmcnt(0)" ::: "memory");
        } else {
            // outstanding (oldest..newest): 16 loads (iter t-1), 64 stores
            // (iter t-1). In-order retirement => <=63 outstanding implies all
            // 16 loads landed (waits on at most 1 store).
            asm volatile("s_waitcnt vmcnt(63)" ::: "memory");
        }
        __builtin_amdgcn_sched_barrier(0);  // rule #18: don't hoist VALU above

        // ---- Pass 1: H_16 across j (stages h=1,2,4,8) ----
#pragma unroll
        for (int hb = 1; hb < 16; hb <<= 1) {
#pragma unroll
            for (int j = 0; j < 16; ++j) {
                if ((j & hb) == 0) {
                    const int k = j | hb;
                    float4 a = v[j], bb = v[k];
                    v[j] = make_float4(a.x + bb.x, a.y + bb.y, a.z + bb.z, a.w + bb.w);
                    v[k] = make_float4(a.x - bb.x, a.y - bb.y, a.z - bb.z, a.w - bb.w);
                }
            }
        }

        // ---- Phase C: regs -> LDS, row-major [1024][32], float4 writes ----
        // word = (16g+j)*32 + w*4: 8 start-banks x 8 g-lanes deep = the b128
        // wave floor (1 KB / 128 B/clk), no conflicts beyond it.
        {
            float4* lp = reinterpret_cast<float4*>(lds) + (size_t)g * 128 + w;
#pragma unroll
            for (int j = 0; j < 16; ++j)
                lp[j * 8] = v[j];
        }
        BAR();  // lgkmcnt(0): phase-C ds_writes (sourcing v) complete -> v dead

        // ---- prefetch tile t+1 into v (pinned; in flight across D..stores) ----
        if (t < TPT - 1) {
            const uint32_t on = baseB + (uint32_t)(dbase + 4 * DC) * 4u;
#pragma unroll
            for (int j = 0; j < 16; ++j)
                GLOAD(v[j], on + (uint32_t)(j * ND) * 4u);
        }

        // ---- Phase D: LDS -> regs, one column per thread ----
        // word = i*512 + j2*32 + c -> bank = c; 2 lanes/bank (j2 pair) = free.
        float u[64];
#pragma unroll
        for (int i = 0; i < 64; ++i)
            u[i] = lds[i * 512 + j2 * 32 + c];
        BAR();  // all phase-D reads complete -> next iter's phase C may overwrite

        // ---- Pass 2: H_64 across i (stages h=16..512) ----
#pragma unroll
        for (int hb = 1; hb < 64; hb <<= 1) {
#pragma unroll
            for (int i = 0; i < 64; ++i) {
                if ((i & hb) == 0) {
                    const int k = i | hb;
                    float a = u[i], bb = u[k];
                    u[i] = a + bb;
                    u[k] = a - bb;
                }
            }
        }

        // ---- direct stores: u[i] -> y[row 16i+j2, col dbase+c] ----
        // per instruction: 64 lanes = 2 j2-rows x 32 c = two full 128 B lines.
        {
            const uint32_t os = baseS + (uint32_t)dbase * 4u;
#pragma unroll
            for (int i = 0; i < 64; ++i)
                GSTORE(os + (uint32_t)i * 32768u, u[i]);
        }
    }
}

extern "C" void kernel_launch(void* const* d_in, const int* in_sizes, int n_in,
                              void* d_out, int out_size, void* d_ws, size_t ws_size,
                              hipStream_t stream) {
    const float* x = (const float*)d_in[0];
    float* y = (float*)d_out;
    fwht_kernel<<<dim3(GRID), dim3(TPB), 0, stream>>>(x, y);
}